// Round 7
// baseline (255.448 us; speedup 1.0000x reference)
//
#include <hip/hip_runtime.h>
#include <stdint.h>

#define HIDDEN 1024
#define HEADS 16
#define HEAD_DIM 64
#define BATCH 4
#define SEQ 2048
#define NTOK (BATCH * SEQ)   // 8192

typedef __attribute__((ext_vector_type(8))) short bf16x8;
typedef __attribute__((ext_vector_type(4))) float floatx4;
typedef __attribute__((ext_vector_type(16))) float floatx16;

// log2(e) / sqrt(HEAD_DIM) : folded into Q so p = exp2(s) directly
#define SCALE_Q 0.18033688011112042f

__device__ __forceinline__ unsigned short f2bf(float f) {
    union { float f; unsigned u; } x; x.f = f;
    unsigned r = x.u + 0x7fffu + ((x.u >> 16) & 1u);
    return (unsigned short)(r >> 16);
}

__device__ __forceinline__ float fast_exp2(float x) {
#if __has_builtin(__builtin_amdgcn_exp2f)
    return __builtin_amdgcn_exp2f(x);
#else
    return exp2f(x);
#endif
}

typedef __attribute__((address_space(3))) unsigned int lds_u32;
typedef const __attribute__((address_space(1))) unsigned int gl_u32;

// async global->LDS, 16B per lane; l is the WAVE-UNIFORM base (HW scatters
// lane i's 16B to l + i*16).
__device__ __forceinline__ void async_cp16(const void* g, void* l) {
#if __has_builtin(__builtin_amdgcn_global_load_lds)
    __builtin_amdgcn_global_load_lds((gl_u32*)g, (lds_u32*)l, 16, 0, 0);
#else
    *(uint4*)((char*)l + (threadIdx.x & 63) * 16) = *(const uint4*)g;
#endif
}

// ---- fused fp32->bf16 conversion for x, Wq, Wk, Wv + zero of accp ----------
__global__ __launch_bounds__(256) void conv_all(
    const float* __restrict__ x, const float* __restrict__ Wq,
    const float* __restrict__ Wk, const float* __restrict__ Wv,
    unsigned short* __restrict__ x_bf, unsigned short* __restrict__ wq_bf,
    unsigned short* __restrict__ wk_bf, unsigned short* __restrict__ wv_bf,
    float* __restrict__ accp) {
    const int blk = blockIdx.x, tid = threadIdx.x;
    const float* src;
    unsigned short* dst;
    size_t i;
    if (blk < 8192) {
        src = x; dst = x_bf; i = (size_t)blk * 256 + tid;
        if (blk < 16) accp[blk * 256 + tid] = 0.0f;
    } else {
        int r = blk - 8192;
        int s = r >> 10;
        src = (s == 0) ? Wq : (s == 1) ? Wk : Wv;
        dst = (s == 0) ? wq_bf : (s == 1) ? wk_bf : wv_bf;
        i = (size_t)(r & 1023) * 256 + tid;
    }
    float4 v = *(const float4*)(src + 4 * i);
    unsigned short o[4];
    o[0] = f2bf(v.x); o[1] = f2bf(v.y); o[2] = f2bf(v.z); o[3] = f2bf(v.w);
    *(ushort4*)(dst + 4 * i) = *(ushort4*)o;
}

// ---- QKV GEMM, m97-style: single N=3072 GEMM of 128x128 tiles --------------
// grid 1536 = 24 nzb x 64 mb (id = nzb*64 + mb => XCD = mb%8: 8 X-strips
// of 2 MB per XCD stay L2-resident; W streams). z = nzb>>3 picks Q/K/V and
// nz = nzb&7 the 128-col slab inside it, so each block has ONE output matrix.
// Tile: 128x128, 4 waves x (64x64), BK=32 double-buffered async staging.
// Per kt: 4 cp16 + 8 ds_read_b128 + 16 MFMA (2.0 MFMA/read).
// k-chunk XOR swizzle (slot = kc ^ (row&3), baked into the staging GLOBAL
// address) cuts frag-read bank conflicts 8-way -> 4-way.
// Epilogue via 34 KB LDS transpose buffer UNIONED with the 32 KB dbuf:
// every global store is >=128 B contiguous per thread.
// z==0 (Q): scaled by SCALE_Q.  z==2 (V): transposed output Vt[bh*64+d][t].
__global__ __launch_bounds__(256, 3) void qkv_gemm(
    const unsigned short* __restrict__ X,
    const unsigned short* __restrict__ W0, const unsigned short* __restrict__ W1,
    const unsigned short* __restrict__ W2,
    const float* __restrict__ b0, const float* __restrict__ b1,
    const float* __restrict__ b2,
    unsigned short* __restrict__ O0, unsigned short* __restrict__ O1,
    unsigned short* __restrict__ O2) {
    __shared__ __align__(16) char smem[34816];   // A dbuf 16K | B dbuf 16K; tbuf aliases
    unsigned short* tbuf = (unsigned short*)smem;

    const int id = blockIdx.x;
    const int mb = id & 63, nzb = id >> 6;
    const int z = nzb >> 3, nz = nzb & 7;
    const int m0 = mb * 128;
    const unsigned short* W = (z == 0) ? W0 : (z == 1) ? W1 : W2;
    const float* bias       = (z == 0) ? b0 : (z == 1) ? b1 : b2;

    const int tid = threadIdx.x, lane = tid & 63, wave = tid >> 6;
    const int wm = (wave & 1) * 64, wn = (wave >> 1) * 64;

    // staging: wave w covers rows [32w, 32w+32): 2 instrs x 16 rows.
    // global column chunk = (l&3) ^ (row&3)  (XOR swizzle baked in)
    const int srow = lane >> 2;
    const int sxc = ((lane & 3) ^ (srow & 3)) * 8;   // shorts
    const unsigned short* ga[2];
    const unsigned short* gb[2];
#pragma unroll
    for (int j = 0; j < 2; ++j) {
        ga[j] = X + (size_t)(m0 + wave * 32 + j * 16 + srow) * HIDDEN + sxc;
        gb[j] = W + (size_t)(nz * 128 + wave * 32 + j * 16 + srow) * HIDDEN + sxc;
    }

    floatx4 acc[4][4];
#pragma unroll
    for (int tm = 0; tm < 4; ++tm)
#pragma unroll
        for (int tn = 0; tn < 4; ++tn)
#pragma unroll
            for (int r = 0; r < 4; ++r) acc[tm][tn][r] = 0.f;

    // prologue: stage tile 0 into buf 0
#pragma unroll
    for (int j = 0; j < 2; ++j) {
        async_cp16(ga[j], smem + wave * 2048 + j * 1024);
        async_cp16(gb[j], smem + 16384 + wave * 2048 + j * 1024);
        ga[j] += 32; gb[j] += 32;
    }
    __syncthreads();

    // frag read: row*64 + (kc ^ (row&3))*16 ; row%4 == lane%4 for all frags
    const int fr = (lane & 15) * 64 + (((lane >> 4) ^ (lane & 3)) * 16);
    for (int kt = 0; kt < 32; ++kt) {
        const int cur = kt & 1;
        if (kt < 31) {
#pragma unroll
            for (int j = 0; j < 2; ++j) {
                async_cp16(ga[j], smem + (cur ^ 1) * 8192 + wave * 2048 + j * 1024);
                async_cp16(gb[j], smem + 16384 + (cur ^ 1) * 8192 + wave * 2048 + j * 1024);
                ga[j] += 32; gb[j] += 32;
            }
        }
        const char* Ab = smem + cur * 8192;
        const char* Bb = smem + 16384 + cur * 8192;
        bf16x8 af[4], bfr[4];
#pragma unroll
        for (int t = 0; t < 4; ++t) {
            af[t]  = *(bf16x8*)(Ab + (wm + t * 16) * 64 + fr);
            bfr[t] = *(bf16x8*)(Bb + (wn + t * 16) * 64 + fr);
        }
#pragma unroll
        for (int tm = 0; tm < 4; ++tm)
#pragma unroll
            for (int tn = 0; tn < 4; ++tn)
                acc[tm][tn] = __builtin_amdgcn_mfma_f32_16x16x32_bf16(af[tm], bfr[tn], acc[tm][tn], 0, 0, 0);
        if (kt < 31) __syncthreads();
    }

    // ---- epilogue via LDS transpose (tbuf aliases the dbuf) ----------------
    // C/D map: col = lane&15, row = (lane>>4)*4 + reg
    const int col = lane & 15, rbase = (lane >> 4) * 4;
    __syncthreads();   // all frag reads done before tbuf overwrites dbuf
    if (z == 2) {
        // V: tbuf [d 0..127][tok 0..127], row stride 136 shorts
#pragma unroll
        for (int tm = 0; tm < 4; ++tm)
#pragma unroll
            for (int tn = 0; tn < 4; ++tn) {
                const int dr = wn + tn * 16 + col;          // 0..127
                const float bs = bias[nz * 128 + dr];
                const int mi0 = wm + tm * 16 + rbase;       // 0..127
                unsigned short vals[4];
#pragma unroll
                for (int r = 0; r < 4; ++r) vals[r] = f2bf(acc[tm][tn][r] + bs);
                *(ushort4*)&tbuf[dr * 136 + mi0] = *(ushort4*)vals;
            }
        __syncthreads();
        // writeback: each thread one 128 B contiguous chunk of a Vt d-row
        const int dr = tid >> 1, seg = tid & 1;
        const int hh = nz * 2 + (dr >> 6), dd = dr & 63;
        const int bb = m0 >> 11, tb = (m0 & (SEQ - 1)) >> 7;
        unsigned short* dst = O2 + (((size_t)bb * HEADS + hh) * HEAD_DIM + dd) * SEQ
                                 + tb * 128 + seg * 64;
        const unsigned short* srcl = &tbuf[dr * 136 + seg * 64];
#pragma unroll
        for (int i = 0; i < 8; ++i)
            *(uint4*)(dst + i * 8) = *(const uint4*)(srcl + i * 8);
    } else {
        unsigned short* O = (z == 0) ? O0 : O1;
        const float sc = (z == 0) ? SCALE_Q : 1.0f;
        // Q/K: tbuf [tok 0..127][n 0..127], row stride 136 shorts
#pragma unroll
        for (int tm = 0; tm < 4; ++tm)
#pragma unroll
            for (int tn = 0; tn < 4; ++tn) {
                const int nn = wn + tn * 16 + col;          // 0..127
                const float bs = bias[nz * 128 + nn];
                const int mi0 = wm + tm * 16 + rbase;
#pragma unroll
                for (int r = 0; r < 4; ++r)
                    tbuf[(mi0 + r) * 136 + nn] = f2bf((acc[tm][tn][r] + bs) * sc);
            }
        __syncthreads();
        // writeback: each thread one 128 B contiguous chunk of a token row
        const int r = tid >> 1, seg = tid & 1;
        unsigned short* dst = O + (size_t)(m0 + r) * HIDDEN + nz * 128 + seg * 64;
        const unsigned short* srcl = &tbuf[r * 136 + seg * 64];
#pragma unroll
        for (int i = 0; i < 8; ++i)
            *(uint4*)(dst + i * 8) = *(const uint4*)(srcl + i * 8);
    }
}

// ---- MFMA flash attention: 256 q/block, async dbuf staging, 1 barrier/iter -
// grid 512 (1-D). XCD swizzle: all 8 q-chunks of one (b,h) land on one XCD.
// Per wave: 2 query-groups of 32. S^T = K·Q^T (C col = query = lane&31).
// PV k-slot permutation: lane g2 natively holds keys {0-3,8-11}+4g2 of each
// 16-key step; A-frag = packed pk regs directly; V B-frag reads those keys
// with two ds_read_b64 (16B-chunk XOR swizzle, baked into staging address).
// l = P·1 ones-MFMA (same reg layout as oacc rows).
__global__ __launch_bounds__(256, 2) void attn_mfma(
    const unsigned short* __restrict__ Q, const unsigned short* __restrict__ K,
    const unsigned short* __restrict__ Vt, float* __restrict__ accp) {
    __shared__ unsigned short Klds[2][8192];  // 128 keys x 64 d, chunk-swizzled
    __shared__ unsigned short Vlds[2][8192];  // 64 d x 128 keys, chunk-swizzled

    const int tid = threadIdx.x, lane = tid & 63, wave = tid >> 6;
    const int lq = lane & 31, g2 = lane >> 5;

    const int f = blockIdx.x;
    const int bh = (f & 7) * 8 + ((f >> 3) & 7);
    const int qc = f >> 6;
    const int b = bh >> 4, h = bh & 15;

    // Q B-fragments: 2 groups x 4 k-slices (cached whole kernel)
    bf16x8 qfrag[2][4];
#pragma unroll
    for (int g = 0; g < 2; ++g) {
        const size_t qb = ((size_t)(b * SEQ + qc * 256 + wave * 64 + g * 32 + lq)) * HIDDEN
                          + h * HEAD_DIM + g2 * 8;
#pragma unroll
        for (int ds = 0; ds < 4; ++ds) qfrag[g][ds] = *(const bf16x8*)&Q[qb + ds * 16];
    }

    // staging pointers. K: wave w covers rows [w*32,w*32+32) (4 instr x 8 rows);
    // V: d-rows [w*16,w*16+16) (4 instr x 4 rows). XOR chunk swizzle baked into
    // the GLOBAL address so lane-linear LDS writes give swizzled layout.
    const unsigned short* kg[4];
    const unsigned short* vg[4];
    {
        const int kr = lane >> 3;                       // row&7
        const int kc = ((lane & 7) ^ kr) * 8;
#pragma unroll
        for (int j = 0; j < 4; ++j)
            kg[j] = K + ((size_t)(b * SEQ + wave * 32 + j * 8 + kr)) * HIDDEN + h * HEAD_DIM + kc;
#pragma unroll
        for (int j = 0; j < 4; ++j) {
            const int dl = wave * 16 + j * 4 + (lane >> 4);
            const int cc = ((lane & 15) ^ (dl & 15)) * 8;
            vg[j] = Vt + ((size_t)bh * HEAD_DIM + dl) * SEQ + cc;
        }
    }

    floatx16 oacc[2][2], lacc[2];
#pragma unroll
    for (int g = 0; g < 2; ++g)
#pragma unroll
        for (int r = 0; r < 16; ++r) { oacc[g][0][r] = 0.f; oacc[g][1][r] = 0.f; lacc[g][r] = 0.f; }

    bf16x8 ones;
    {
        union { bf16x8 v; unsigned u[4]; } o;
        o.u[0] = o.u[1] = o.u[2] = o.u[3] = 0x3F803F80u;
        ones = o.v;
    }

    // prologue: stage tile 0 into buf 0
#pragma unroll
    for (int j = 0; j < 4; ++j) {
        async_cp16(kg[j], (char*)Klds[0] + (wave * 32 + j * 8) * 128);
        async_cp16(vg[j], (char*)Vlds[0] + (wave * 16 + j * 4) * 256);
        kg[j] += 128 * HIDDEN; vg[j] += 128;
    }
    __syncthreads();

    for (int it = 0; it < 16; ++it) {
        const int cur = it & 1;
        if (it < 15) {
#pragma unroll
            for (int j = 0; j < 4; ++j) {
                async_cp16(kg[j], (char*)Klds[cur ^ 1] + (wave * 32 + j * 8) * 128);
                async_cp16(vg[j], (char*)Vlds[cur ^ 1] + (wave * 16 + j * 4) * 256);
                kg[j] += 128 * HIDDEN; vg[j] += 128;
            }
        }
#pragma unroll
        for (int ks4 = 0; ks4 < 4; ++ks4) {
            const int kk = ks4 * 32;
            const int rr = kk + lq;
            bf16x8 kf[4];
#pragma unroll
            for (int ds = 0; ds < 4; ++ds)
                kf[ds] = *(bf16x8*)((char*)Klds[cur] + rr * 128 + (((g2 + 2 * ds) ^ (lq & 7)) * 16));

            unsigned pk[2][8];
#pragma unroll
            for (int g = 0; g < 2; ++g) {
                floatx16 sacc;
#pragma unroll
                for (int r = 0; r < 16; ++r) sacc[r] = 0.f;
#pragma unroll
                for (int ds = 0; ds < 4; ++ds)
                    sacc = __builtin_amdgcn_mfma_f32_32x32x16_bf16(kf[ds], qfrag[g][ds], sacc, 0, 0, 0);
#pragma unroll
                for (int j = 0; j < 8; ++j) {
                    union { float f; unsigned u; } plo, phi;
                    plo.f = fast_exp2(sacc[2 * j]);
                    phi.f = fast_exp2(sacc[2 * j + 1]);
                    pk[g][j] = __builtin_amdgcn_perm(phi.u, plo.u, 0x07060302u);
                }
            }
#pragma unroll
            for (int ks2 = 0; ks2 < 2; ++ks2) {
                // V B-frags at this lane's native keys: bases kk+16ks2+4g2, +8.
                bf16x8 vf[2];
#pragma unroll
                for (int nf = 0; nf < 2; ++nf) {
                    const int d = nf * 32 + lq;
                    const int c0 = (4 * ks4 + 2 * ks2) ^ (d & 15);
                    const int c1 = (4 * ks4 + 2 * ks2 + 1) ^ (d & 15);
                    union { uint2 h[2]; bf16x8 v; } u;
                    u.h[0] = *(uint2*)((char*)Vlds[cur] + d * 256 + c0 * 16 + g2 * 8);
                    u.h[1] = *(uint2*)((char*)Vlds[cur] + d * 256 + c1 * 16 + g2 * 8);
                    vf[nf] = u.v;
                }
#pragma unroll
                for (int g = 0; g < 2; ++g) {
                    union { uint4 u; bf16x8 v; } af;
                    af.u.x = pk[g][4 * ks2];
                    af.u.y = pk[g][4 * ks2 + 1];
                    af.u.z = pk[g][4 * ks2 + 2];
                    af.u.w = pk[g][4 * ks2 + 3];
#pragma unroll
                    for (int nf = 0; nf < 2; ++nf)
                        oacc[g][nf] = __builtin_amdgcn_mfma_f32_32x32x16_bf16(af.v, vf[nf], oacc[g][nf], 0, 0, 0);
                    lacc[g] = __builtin_amdgcn_mfma_f32_32x32x16_bf16(af.v, ones, lacc[g], 0, 0, 0);
                }
            }
        }
        if (it < 15) __syncthreads();
    }

    // epilogue: d-col = lane&31 (+32*nf); sum_q o/l over each group's 32 rows
#pragma unroll
    for (int g = 0; g < 2; ++g)
#pragma unroll
        for (int nf = 0; nf < 2; ++nf) {
            float v = 0.f;
#pragma unroll
            for (int r = 0; r < 16; ++r) v += oacc[g][nf][r] / lacc[g][r];
            v += __shfl_xor(v, 32, 64);
            if (lane < 32)
                atomicAdd(&accp[b * HIDDEN + h * HEAD_DIM + nf * 32 + lq], v);
        }
}

// ---- final projection: out = (acc/T) @ Wo^T + bo, split-k x4 ---------------
__global__ __launch_bounds__(256) void out_proj(const float* __restrict__ acc,
                                                const float* __restrict__ Wo,
                                                const float* __restrict__ bo,
                                                float* __restrict__ out) {
    __shared__ float red[256];
    const int n = blockIdx.x * 64 + (threadIdx.x & 63);
    const int ks = threadIdx.x >> 6;       // 0..3
    const int b = blockIdx.y;
    const float* wr = Wo + (size_t)n * HIDDEN + ks * 256;
    const float* ar = acc + b * HIDDEN + ks * 256;
    float s = 0.f;
#pragma unroll 8
    for (int k = 0; k < 256; k += 4) {
        float4 w = *(const float4*)(wr + k);
        float4 a = *(const float4*)(ar + k);
        s += w.x * a.x + w.y * a.y + w.z * a.z + w.w * a.w;
    }
    red[threadIdx.x] = s;
    __syncthreads();
    if (threadIdx.x < 64) {
        float t = red[threadIdx.x] + red[threadIdx.x + 64]
                + red[threadIdx.x + 128] + red[threadIdx.x + 192];
        out[b * HIDDEN + n] = t * (1.0f / (float)SEQ) + bo[n];
    }
}

extern "C" void kernel_launch(void* const* d_in, const int* in_sizes, int n_in,
                              void* d_out, int out_size, void* d_ws, size_t ws_size,
                              hipStream_t stream) {
    const float* x  = (const float*)d_in[0];
    const float* Wq = (const float*)d_in[1];
    const float* bq = (const float*)d_in[2];
    const float* Wk = (const float*)d_in[3];
    const float* bk = (const float*)d_in[4];
    const float* Wv = (const float*)d_in[5];
    const float* bv = (const float*)d_in[6];
    const float* Wo = (const float*)d_in[7];
    const float* bo = (const float*)d_in[8];
    float* out = (float*)d_out;

    char* ws = (char*)d_ws;
    unsigned short* x_bf  = (unsigned short*)(ws);                      // 16 MB
    unsigned short* wq_bf = (unsigned short*)(ws + 16777216);           //  2 MB
    unsigned short* wk_bf = (unsigned short*)(ws + 18874368);           //  2 MB
    unsigned short* wv_bf = (unsigned short*)(ws + 20971520);           //  2 MB
    unsigned short* q_bf  = (unsigned short*)(ws + 23068672);           // 16 MB (pre-scaled Q)
    unsigned short* k_bf  = (unsigned short*)(ws + 39845888);           // 16 MB
    unsigned short* vt_bf = (unsigned short*)(ws + 56623104);           // 16 MB (V^T)
    float*          accp  = (float*)(ws + 73400320);                    // 16 KB

    conv_all<<<dim3(8192 + 3072), dim3(256), 0, stream>>>(
        x, Wq, Wk, Wv, x_bf, wq_bf, wk_bf, wv_bf, accp);

    qkv_gemm<<<dim3(1536), dim3(256), 0, stream>>>(
        x_bf, wq_bf, wk_bf, wv_bf, bq, bk, bv, q_bf, k_bf, vt_bf);

    attn_mfma<<<dim3(512), dim3(256), 0, stream>>>(q_bf, k_bf, vt_bf, accp);

    out_proj<<<dim3(16, BATCH), dim3(256), 0, stream>>>(accp, Wo, bo, out);
}

// Round 8
// 250.802 us; speedup vs baseline: 1.0185x; 1.0185x over previous
//
#include <hip/hip_runtime.h>
#include <stdint.h>

#define HIDDEN 1024
#define HEADS 16
#define HEAD_DIM 64
#define BATCH 4
#define SEQ 2048
#define NTOK (BATCH * SEQ)   // 8192

typedef __attribute__((ext_vector_type(8))) short bf16x8;
typedef __attribute__((ext_vector_type(4))) float floatx4;
typedef __attribute__((ext_vector_type(16))) float floatx16;

// log2(e) / sqrt(HEAD_DIM) : folded into Q so p = exp2(s) directly
#define SCALE_Q 0.18033688011112042f

__device__ __forceinline__ unsigned short f2bf(float f) {
    union { float f; unsigned u; } x; x.f = f;
    unsigned r = x.u + 0x7fffu + ((x.u >> 16) & 1u);
    return (unsigned short)(r >> 16);
}

__device__ __forceinline__ float fast_exp2(float x) {
#if __has_builtin(__builtin_amdgcn_exp2f)
    return __builtin_amdgcn_exp2f(x);
#else
    return exp2f(x);
#endif
}

typedef __attribute__((address_space(3))) unsigned int lds_u32;
typedef const __attribute__((address_space(1))) unsigned int gl_u32;

// async global->LDS, 16B per lane; l is the WAVE-UNIFORM base (HW scatters
// lane i's 16B to l + i*16).
__device__ __forceinline__ void async_cp16(const void* g, void* l) {
#if __has_builtin(__builtin_amdgcn_global_load_lds)
    __builtin_amdgcn_global_load_lds((gl_u32*)g, (lds_u32*)l, 16, 0, 0);
#else
    *(uint4*)((char*)l + (threadIdx.x & 63) * 16) = *(const uint4*)g;
#endif
}

// ---- fused fp32->bf16 conversion for x, Wq, Wk, Wv + zero of accp ----------
__global__ __launch_bounds__(256) void conv_all(
    const float* __restrict__ x, const float* __restrict__ Wq,
    const float* __restrict__ Wk, const float* __restrict__ Wv,
    unsigned short* __restrict__ x_bf, unsigned short* __restrict__ wq_bf,
    unsigned short* __restrict__ wk_bf, unsigned short* __restrict__ wv_bf,
    float* __restrict__ accp) {
    const int blk = blockIdx.x, tid = threadIdx.x;
    const float* src;
    unsigned short* dst;
    size_t i;
    if (blk < 8192) {
        src = x; dst = x_bf; i = (size_t)blk * 256 + tid;
        if (blk < 16) accp[blk * 256 + tid] = 0.0f;
    } else {
        int r = blk - 8192;
        int s = r >> 10;
        src = (s == 0) ? Wq : (s == 1) ? Wk : Wv;
        dst = (s == 0) ? wq_bf : (s == 1) ? wk_bf : wv_bf;
        i = (size_t)(r & 1023) * 256 + tid;
    }
    float4 v = *(const float4*)(src + 4 * i);
    unsigned short o[4];
    o[0] = f2bf(v.x); o[1] = f2bf(v.y); o[2] = f2bf(v.z); o[3] = f2bf(v.w);
    *(ushort4*)(dst + 4 * i) = *(ushort4*)o;
}

// ---- QKV GEMM, single N=3072 GEMM of 128x128 tiles -------------------------
// grid 1536 = 24 nzb x 64 mb (XCD = mb%8). Tile: 128x128, 4 waves x (64x64),
// BK=32 double-buffered async staging. Epilogue via LDS transpose buffer
// (aliases the dbuf): every global store is 128 B contiguous per thread.
// z==0 (Q): scaled by SCALE_Q.  z==2 (V): transposed output Vt[bh*64+d][t]
// with key-granule PERMUTATION (swap bits 2,3 of key index) so the attention
// kernel's PV B-frag (keys {0-3,8-11}+4g2 of a 16-key step) is one b128.
__global__ __launch_bounds__(256, 3) void qkv_gemm(
    const unsigned short* __restrict__ X,
    const unsigned short* __restrict__ W0, const unsigned short* __restrict__ W1,
    const unsigned short* __restrict__ W2,
    const float* __restrict__ b0, const float* __restrict__ b1,
    const float* __restrict__ b2,
    unsigned short* __restrict__ O0, unsigned short* __restrict__ O1,
    unsigned short* __restrict__ O2) {
    __shared__ __align__(16) char smem[34816];   // A dbuf 16K | B dbuf 16K; tbuf aliases
    unsigned short* tbuf = (unsigned short*)smem;

    const int id = blockIdx.x;
    const int mb = id & 63, nzb = id >> 6;
    const int z = nzb >> 3, nz = nzb & 7;
    const int m0 = mb * 128;
    const unsigned short* W = (z == 0) ? W0 : (z == 1) ? W1 : W2;
    const float* bias       = (z == 0) ? b0 : (z == 1) ? b1 : b2;

    const int tid = threadIdx.x, lane = tid & 63, wave = tid >> 6;
    const int wm = (wave & 1) * 64, wn = (wave >> 1) * 64;

    // staging: wave w covers rows [32w, 32w+32): 2 instrs x 16 rows.
    // global column chunk = (l&3) ^ (row&3)  (XOR swizzle baked in)
    const int srow = lane >> 2;
    const int sxc = ((lane & 3) ^ (srow & 3)) * 8;   // shorts
    const unsigned short* ga[2];
    const unsigned short* gb[2];
#pragma unroll
    for (int j = 0; j < 2; ++j) {
        ga[j] = X + (size_t)(m0 + wave * 32 + j * 16 + srow) * HIDDEN + sxc;
        gb[j] = W + (size_t)(nz * 128 + wave * 32 + j * 16 + srow) * HIDDEN + sxc;
    }

    floatx4 acc[4][4];
#pragma unroll
    for (int tm = 0; tm < 4; ++tm)
#pragma unroll
        for (int tn = 0; tn < 4; ++tn)
#pragma unroll
            for (int r = 0; r < 4; ++r) acc[tm][tn][r] = 0.f;

    // prologue: stage tile 0 into buf 0
#pragma unroll
    for (int j = 0; j < 2; ++j) {
        async_cp16(ga[j], smem + wave * 2048 + j * 1024);
        async_cp16(gb[j], smem + 16384 + wave * 2048 + j * 1024);
        ga[j] += 32; gb[j] += 32;
    }
    __syncthreads();

    // frag read: row*64 + (kc ^ (row&3))*16 ; row%4 == lane%4 for all frags
    const int fr = (lane & 15) * 64 + (((lane >> 4) ^ (lane & 3)) * 16);
    for (int kt = 0; kt < 32; ++kt) {
        const int cur = kt & 1;
        if (kt < 31) {
#pragma unroll
            for (int j = 0; j < 2; ++j) {
                async_cp16(ga[j], smem + (cur ^ 1) * 8192 + wave * 2048 + j * 1024);
                async_cp16(gb[j], smem + 16384 + (cur ^ 1) * 8192 + wave * 2048 + j * 1024);
                ga[j] += 32; gb[j] += 32;
            }
        }
        const char* Ab = smem + cur * 8192;
        const char* Bb = smem + 16384 + cur * 8192;
        bf16x8 af[4], bfr[4];
#pragma unroll
        for (int t = 0; t < 4; ++t) {
            af[t]  = *(bf16x8*)(Ab + (wm + t * 16) * 64 + fr);
            bfr[t] = *(bf16x8*)(Bb + (wn + t * 16) * 64 + fr);
        }
#pragma unroll
        for (int tm = 0; tm < 4; ++tm)
#pragma unroll
            for (int tn = 0; tn < 4; ++tn)
                acc[tm][tn] = __builtin_amdgcn_mfma_f32_16x16x32_bf16(af[tm], bfr[tn], acc[tm][tn], 0, 0, 0);
        if (kt < 31) __syncthreads();
    }

    // ---- epilogue via LDS transpose (tbuf aliases the dbuf) ----------------
    // C/D map: col = lane&15, row = (lane>>4)*4 + reg
    const int col = lane & 15, rbase = (lane >> 4) * 4;
    __syncthreads();   // all frag reads done before tbuf overwrites dbuf
    if (z == 2) {
        // V: tbuf [d 0..127][tok 0..127], row stride 136 shorts.
        // Key-granule permutation: swap bits 2,3 of the token index (granule
        // pos within each 16-key group) -> PV B-frag is one b128 in attn.
#pragma unroll
        for (int tm = 0; tm < 4; ++tm)
#pragma unroll
            for (int tn = 0; tn < 4; ++tn) {
                const int dr = wn + tn * 16 + col;          // 0..127
                const float bs = bias[nz * 128 + dr];
                const int mi0 = wm + tm * 16 + rbase;       // 0..127, mult of 4
                const int mip = (mi0 & ~12) | ((mi0 & 4) << 1) | ((mi0 & 8) >> 1);
                unsigned short vals[4];
#pragma unroll
                for (int r = 0; r < 4; ++r) vals[r] = f2bf(acc[tm][tn][r] + bs);
                *(ushort4*)&tbuf[dr * 136 + mip] = *(ushort4*)vals;
            }
        __syncthreads();
        // writeback: each thread one 128 B contiguous chunk of a Vt d-row
        const int dr = tid >> 1, seg = tid & 1;
        const int hh = nz * 2 + (dr >> 6), dd = dr & 63;
        const int bb = m0 >> 11, tb = (m0 & (SEQ - 1)) >> 7;
        unsigned short* dst = O2 + (((size_t)bb * HEADS + hh) * HEAD_DIM + dd) * SEQ
                                 + tb * 128 + seg * 64;
        const unsigned short* srcl = &tbuf[dr * 136 + seg * 64];
#pragma unroll
        for (int i = 0; i < 8; ++i)
            *(uint4*)(dst + i * 8) = *(const uint4*)(srcl + i * 8);
    } else {
        unsigned short* O = (z == 0) ? O0 : O1;
        const float sc = (z == 0) ? SCALE_Q : 1.0f;
        // Q/K: tbuf [tok 0..127][n 0..127], row stride 136 shorts
#pragma unroll
        for (int tm = 0; tm < 4; ++tm)
#pragma unroll
            for (int tn = 0; tn < 4; ++tn) {
                const int nn = wn + tn * 16 + col;          // 0..127
                const float bs = bias[nz * 128 + nn];
                const int mi0 = wm + tm * 16 + rbase;
#pragma unroll
                for (int r = 0; r < 4; ++r)
                    tbuf[(mi0 + r) * 136 + nn] = f2bf((acc[tm][tn][r] + bs) * sc);
            }
        __syncthreads();
        // writeback: each thread one 128 B contiguous chunk of a token row
        const int r = tid >> 1, seg = tid & 1;
        unsigned short* dst = O + (size_t)(m0 + r) * HIDDEN + nz * 128 + seg * 64;
        const unsigned short* srcl = &tbuf[r * 136 + seg * 64];
#pragma unroll
        for (int i = 0; i < 8; ++i)
            *(uint4*)(dst + i * 8) = *(const uint4*)(srcl + i * 8);
    }
}

// ---- MFMA flash attention: 128 q/block, 64-key dbuf tiles, 4 blocks/CU -----
// grid 1024. XCD swizzle: all 16 q-chunks of one (b,h) land on one XCD.
// One q-group of 32 per wave (AGPR 64). S^T = K·Q^T (C col = query).
// PV: lane g2 natively holds keys {0-3,8-11}+4g2 of each 16-key step;
// A-frag = packed pk regs; V B-frag is ONE b128 thanks to the key-granule
// permutation baked into Vt by qkv_gemm. l = P·1 ones-MFMA.
__global__ __launch_bounds__(256, 4) void attn_mfma(
    const unsigned short* __restrict__ Q, const unsigned short* __restrict__ K,
    const unsigned short* __restrict__ Vt, float* __restrict__ accp) {
    __shared__ unsigned short Klds[2][4096];  // 64 keys x 64 d, chunk-swizzled
    __shared__ unsigned short Vlds[2][4096];  // 64 d x 64 keys (perm), swizzled

    const int tid = threadIdx.x, lane = tid & 63, wave = tid >> 6;
    const int lq = lane & 31, g2 = lane >> 5;

    const int f = blockIdx.x;
    const int bh = (f & 7) * 8 + ((f >> 3) & 7);
    const int qc = f >> 6;                    // 0..15 (128-q chunk)
    const int b = bh >> 4, h = bh & 15;

    // Q B-fragments: 1 group of 32 q per wave, 4 k-slices
    bf16x8 qfrag[4];
    {
        const size_t qb = ((size_t)(b * SEQ + qc * 128 + wave * 32 + lq)) * HIDDEN
                          + h * HEAD_DIM + g2 * 8;
#pragma unroll
        for (int ds = 0; ds < 4; ++ds) qfrag[ds] = *(const bf16x8*)&Q[qb + ds * 16];
    }

    // staging pointers. K: wave w covers rows [16w,16w+16) (2 instr x 8 rows);
    // V: d-rows [16w,16w+16). XOR chunk swizzle baked into the GLOBAL address
    // so lane-linear LDS writes give the swizzled layout.
    const unsigned short* kg[2];
    const unsigned short* vg[2];
    {
        const int kr = lane >> 3;                       // 0..7
        const int kc = ((lane & 7) ^ kr) * 8;
#pragma unroll
        for (int j = 0; j < 2; ++j)
            kg[j] = K + ((size_t)(b * SEQ + wave * 16 + j * 8 + kr)) * HIDDEN + h * HEAD_DIM + kc;
#pragma unroll
        for (int j = 0; j < 2; ++j) {
            const int dl = wave * 16 + j * 8 + (lane >> 3);
            const int cc = ((lane & 7) ^ (dl & 7)) * 8;
            vg[j] = Vt + ((size_t)bh * HEAD_DIM + dl) * SEQ + cc;
        }
    }

    floatx16 oacc[2], lacc;
#pragma unroll
    for (int r = 0; r < 16; ++r) { oacc[0][r] = 0.f; oacc[1][r] = 0.f; lacc[r] = 0.f; }

    bf16x8 ones;
    {
        union { bf16x8 v; unsigned u[4]; } o;
        o.u[0] = o.u[1] = o.u[2] = o.u[3] = 0x3F803F80u;
        ones = o.v;
    }

    // prologue: stage tile 0 into buf 0
#pragma unroll
    for (int j = 0; j < 2; ++j) {
        async_cp16(kg[j], (char*)Klds[0] + (wave * 16 + j * 8) * 128);
        async_cp16(vg[j], (char*)Vlds[0] + (wave * 16 + j * 8) * 128);
        kg[j] += 64 * HIDDEN; vg[j] += 64;
    }
    __syncthreads();

    for (int it = 0; it < 32; ++it) {
        const int cur = it & 1;
        if (it < 31) {
#pragma unroll
            for (int j = 0; j < 2; ++j) {
                async_cp16(kg[j], (char*)Klds[cur ^ 1] + (wave * 16 + j * 8) * 128);
                async_cp16(vg[j], (char*)Vlds[cur ^ 1] + (wave * 16 + j * 8) * 128);
                kg[j] += 64 * HIDDEN; vg[j] += 64;
            }
        }
#pragma unroll
        for (int s32 = 0; s32 < 2; ++s32) {
            const int rr = s32 * 32 + lq;
            bf16x8 kf[4];
#pragma unroll
            for (int ds = 0; ds < 4; ++ds)
                kf[ds] = *(bf16x8*)((char*)Klds[cur] + rr * 128 + (((g2 + 2 * ds) ^ (lq & 7)) * 16));

            floatx16 sacc;
#pragma unroll
            for (int r = 0; r < 16; ++r) sacc[r] = 0.f;
#pragma unroll
            for (int ds = 0; ds < 4; ++ds)
                sacc = __builtin_amdgcn_mfma_f32_32x32x16_bf16(kf[ds], qfrag[ds], sacc, 0, 0, 0);

            unsigned pk[8];
#pragma unroll
            for (int j = 0; j < 8; ++j) {
                union { float f; unsigned u; } plo, phi;
                plo.f = fast_exp2(sacc[2 * j]);
                phi.f = fast_exp2(sacc[2 * j + 1]);
                pk[j] = __builtin_amdgcn_perm(phi.u, plo.u, 0x07060302u);
            }
#pragma unroll
            for (int ks2 = 0; ks2 < 2; ++ks2) {
                const int s = s32 * 2 + ks2;     // 16-key step 0..3
                bf16x8 vf[2];
#pragma unroll
                for (int nf = 0; nf < 2; ++nf) {
                    const int d = nf * 32 + lq;
                    const int c = (2 * s + g2) ^ (d & 7);
                    vf[nf] = *(bf16x8*)((char*)Vlds[cur] + d * 128 + c * 16);
                }
                union { uint4 u; bf16x8 v; } af;
                af.u.x = pk[4 * ks2];
                af.u.y = pk[4 * ks2 + 1];
                af.u.z = pk[4 * ks2 + 2];
                af.u.w = pk[4 * ks2 + 3];
#pragma unroll
                for (int nf = 0; nf < 2; ++nf)
                    oacc[nf] = __builtin_amdgcn_mfma_f32_32x32x16_bf16(af.v, vf[nf], oacc[nf], 0, 0, 0);
                lacc = __builtin_amdgcn_mfma_f32_32x32x16_bf16(af.v, ones, lacc, 0, 0, 0);
            }
        }
        if (it < 31) __syncthreads();
    }

    // epilogue: d-col = lane&31 (+32*nf); sum_q o/l over the group's 32 rows
#pragma unroll
    for (int nf = 0; nf < 2; ++nf) {
        float v = 0.f;
#pragma unroll
        for (int r = 0; r < 16; ++r) v += oacc[nf][r] / lacc[r];
        v += __shfl_xor(v, 32, 64);
        if (lane < 32)
            atomicAdd(&accp[b * HIDDEN + h * HEAD_DIM + nf * 32 + lq], v);
    }
}

// ---- final projection: out = (acc/T) @ Wo^T + bo, split-k x4 ---------------
__global__ __launch_bounds__(256) void out_proj(const float* __restrict__ acc,
                                                const float* __restrict__ Wo,
                                                const float* __restrict__ bo,
                                                float* __restrict__ out) {
    __shared__ float red[256];
    const int n = blockIdx.x * 64 + (threadIdx.x & 63);
    const int ks = threadIdx.x >> 6;       // 0..3
    const int b = blockIdx.y;
    const float* wr = Wo + (size_t)n * HIDDEN + ks * 256;
    const float* ar = acc + b * HIDDEN + ks * 256;
    float s = 0.f;
#pragma unroll 8
    for (int k = 0; k < 256; k += 4) {
        float4 w = *(const float4*)(wr + k);
        float4 a = *(const float4*)(ar + k);
        s += w.x * a.x + w.y * a.y + w.z * a.z + w.w * a.w;
    }
    red[threadIdx.x] = s;
    __syncthreads();
    if (threadIdx.x < 64) {
        float t = red[threadIdx.x] + red[threadIdx.x + 64]
                + red[threadIdx.x + 128] + red[threadIdx.x + 192];
        out[b * HIDDEN + n] = t * (1.0f / (float)SEQ) + bo[n];
    }
}

extern "C" void kernel_launch(void* const* d_in, const int* in_sizes, int n_in,
                              void* d_out, int out_size, void* d_ws, size_t ws_size,
                              hipStream_t stream) {
    const float* x  = (const float*)d_in[0];
    const float* Wq = (const float*)d_in[1];
    const float* bq = (const float*)d_in[2];
    const float* Wk = (const float*)d_in[3];
    const float* bk = (const float*)d_in[4];
    const float* Wv = (const float*)d_in[5];
    const float* bv = (const float*)d_in[6];
    const float* Wo = (const float*)d_in[7];
    const float* bo = (const float*)d_in[8];
    float* out = (float*)d_out;

    char* ws = (char*)d_ws;
    unsigned short* x_bf  = (unsigned short*)(ws);                      // 16 MB
    unsigned short* wq_bf = (unsigned short*)(ws + 16777216);           //  2 MB
    unsigned short* wk_bf = (unsigned short*)(ws + 18874368);           //  2 MB
    unsigned short* wv_bf = (unsigned short*)(ws + 20971520);           //  2 MB
    unsigned short* q_bf  = (unsigned short*)(ws + 23068672);           // 16 MB (pre-scaled Q)
    unsigned short* k_bf  = (unsigned short*)(ws + 39845888);           // 16 MB
    unsigned short* vt_bf = (unsigned short*)(ws + 56623104);           // 16 MB (V^T, granule-perm)
    float*          accp  = (float*)(ws + 73400320);                    // 16 KB

    conv_all<<<dim3(8192 + 3072), dim3(256), 0, stream>>>(
        x, Wq, Wk, Wv, x_bf, wq_bf, wk_bf, wv_bf, accp);

    qkv_gemm<<<dim3(1536), dim3(256), 0, stream>>>(
        x_bf, wq_bf, wk_bf, wv_bf, bq, bk, bv, q_bf, k_bf, vt_bf);

    attn_mfma<<<dim3(1024), dim3(256), 0, stream>>>(q_bf, k_bf, vt_bf, accp);

    out_proj<<<dim3(16, BATCH), dim3(256), 0, stream>>>(accp, Wo, bo, out);
}